// Round 8
// baseline (176.022 us; speedup 1.0000x reference)
//
#include <hip/hip_runtime.h>
#include <hip/hip_bf16.h>

// Retention: out = (tril(alpha^(i-j)) * (QK^T/sqrt(d))) @ V, qkv = x@W + b
// Decay folded into operands: Q' = q*alpha^i/sqrt(d), K' = k*alpha^(-j)
// Shared GEMM core: 128(M)x256(N) tile, 4 waves (1Mx4N, per-wave 128x64,
// acc[8][4]), BK=32 double-buffered = 48KB LDS -> 2 blocks/CU, 256 threads.
// LDS packing: 2 rows per 128B line, slot = ((row&1)*4+lg) ^ ((row>>1)&7)
// (r6 math, measured 0 bank conflicts), staged via pre-swizzled global source
// with linear gload_lds dest. r5's proven 2-barrier counted-vmcnt loop.
// Geometry rationale: LDS bytes/FLOP = 1/128 + 1/64 = 0.023 -> LDS no longer
// the binding pipe; 2 independent blocks/CU provide the wave-level overlap.

#define SEQ   1024
#define DIM   768
#define ND3   2304

typedef __attribute__((ext_vector_type(8))) short bf16x8;
typedef __attribute__((ext_vector_type(4))) float f32x4;

#define L2A     (-0.014499569695115089f)   // log2(0.99)
#define RSQRTD  (0.03608439182435161f)     // 1/sqrt(768)

__device__ __forceinline__ unsigned short f2bf(float x) {
  union { float f; unsigned u; } v; v.f = x;
  unsigned r = v.u + 0x7FFFu + ((v.u >> 16) & 1u);
  return (unsigned short)(r >> 16);
}

__device__ __forceinline__ void gload16(const void* g, void* l) {
  __builtin_amdgcn_global_load_lds(
      (const __attribute__((address_space(1))) void*)g,
      (__attribute__((address_space(3))) void*)l, 16, 0, 0);
}

// ---- core: acc[8][4] += A[128 x nt*32] @ B[256 x nt*32]^T (row-major, K contig)
// gA/gB: per-lane pre-swizzled staging sources:
//   c8 = (lane&7)^(lane>>3); rloc = (lane>>3)*2 + (c8>>2); colo = (c8&3)*8
//   gA = Abase + (m0 + rloc)*ldA + colo ; gB = Bbase + (n0 + rloc)*ldB + colo
// Per K-tile staging: A 8x1KB chunks (wave w: rows 32w..32w+31),
//                     B 16x1KB chunks (wave w: rows 64w..64w+63). 6 gloads/wave.
__device__ __forceinline__ void gemm_core(
    const unsigned short* gA, const unsigned short* gB, int ldA, int ldB,
    char* lsA, char* lsB, int nt, int wid, int lane, f32x4 acc[8][4]) {
  int lr = lane & 15, lg = lane >> 4;
  int myslot = (((((lr & 1) << 2) | lg) ^ ((lr >> 1) & 7)) << 4);
  int rdA = (lr >> 1) * 128 + myslot;                 // + f*1024 + par*8192
  int rdB = wid * 4096 + (lr >> 1) * 128 + myslot;    // + n*1024 + par*16384

#define STAGE(t, par) do {                                                    \
    char* la_ = lsA + (par) * 8192;                                           \
    char* lb_ = lsB + (par) * 16384;                                          \
    const unsigned short* sa_ = gA + (size_t)(t) * 32;                        \
    const unsigned short* sb_ = gB + (size_t)(t) * 32;                        \
    gload16(sa_ + (size_t)(wid * 32) * ldA,      la_ + wid * 2048);           \
    gload16(sa_ + (size_t)(wid * 32 + 16) * ldA, la_ + wid * 2048 + 1024);    \
    _Pragma("unroll")                                                         \
    for (int c_ = 0; c_ < 4; ++c_)                                            \
      gload16(sb_ + (size_t)((wid * 4 + c_) * 16) * ldB,                      \
              lb_ + (wid * 4 + c_) * 1024);                                   \
  } while (0)

  STAGE(0, 0);
  STAGE(1, 1);
  asm volatile("s_waitcnt vmcnt(6)" ::: "memory");   // tile 0 ready
  __builtin_amdgcn_s_barrier();
  asm volatile("" ::: "memory");

  for (int t = 0; t < nt; ++t) {
    int pA = (t & 1) * 8192, pB = (t & 1) * 16384;
    bf16x8 bF[4];
#pragma unroll
    for (int n = 0; n < 4; ++n)
      bF[n] = *(const bf16x8*)(lsB + pB + rdB + n * 1024);
#pragma unroll
    for (int h = 0; h < 2; ++h) {            // two f-halves to limit live regs
      bf16x8 aF[4];
#pragma unroll
      for (int f = 0; f < 4; ++f)
        aF[f] = *(const bf16x8*)(lsA + pA + rdA + (h * 4 + f) * 1024);
      __builtin_amdgcn_s_setprio(1);
#pragma unroll
      for (int f = 0; f < 4; ++f)
#pragma unroll
        for (int n = 0; n < 4; ++n)
          acc[h * 4 + f][n] = __builtin_amdgcn_mfma_f32_16x16x32_bf16(
              aF[f], bF[n], acc[h * 4 + f][n], 0, 0, 0);
      __builtin_amdgcn_s_setprio(0);
    }

    if (t == nt - 1) break;
    __builtin_amdgcn_s_barrier();            // all reads of this parity done
    asm volatile("" ::: "memory");
    if (t + 2 < nt) {
      STAGE(t + 2, t & 1);                   // refill buffer tile t used
      asm volatile("s_waitcnt vmcnt(6)" ::: "memory");   // tile t+1 ready
    } else {
      asm volatile("s_waitcnt vmcnt(0)" ::: "memory");   // drain last tile
    }
    __builtin_amdgcn_s_barrier();
    asm volatile("" ::: "memory");
  }
#undef STAGE
}

// ---------------- prep: convert x f32->bf16 (6144 blocks) + transpose W (432)
__global__ void prep(const float* __restrict__ x, unsigned short* __restrict__ xb,
                     const float* __restrict__ W, unsigned short* __restrict__ Wt) {
  __shared__ float tile[64][65];
  int bid = blockIdx.x;
  if (bid < 6144) {               // convert_x
    size_t i = ((size_t)bid * 256 + threadIdx.x) * 8;
    float4 f0 = *(const float4*)(x + i);
    float4 f1 = *(const float4*)(x + i + 4);
    bf16x8 v;
    v[0] = (short)f2bf(f0.x); v[1] = (short)f2bf(f0.y);
    v[2] = (short)f2bf(f0.z); v[3] = (short)f2bf(f0.w);
    v[4] = (short)f2bf(f1.x); v[5] = (short)f2bf(f1.y);
    v[6] = (short)f2bf(f1.z); v[7] = (short)f2bf(f1.w);
    *(bf16x8*)(xb + i) = v;
  } else {                        // transpose_w
    int tb = bid - 6144;
    int n0 = (tb % 36) * 64;
    int k0 = (tb / 36) * 64;
    int tx = threadIdx.x & 63, ty = threadIdx.x >> 6;
#pragma unroll
    for (int p = 0; p < 16; ++p) {
      int k = ty + p * 4;
      tile[k][tx] = W[(size_t)(k0 + k) * ND3 + n0 + tx];
    }
    __syncthreads();
#pragma unroll
    for (int p = 0; p < 16; ++p) {
      int n = ty + p * 4;
      Wt[(size_t)(n0 + n) * DIM + k0 + tx] = f2bf(tile[tx][n]);
    }
  }
}

// ---------------- QKV: xb[16384][768] @ Wt^T -> Q',K',Vt. grid 1152 = 128mt x 9nt
__global__ void __launch_bounds__(256, 2) qkv_g(
    const unsigned short* __restrict__ xb, const unsigned short* __restrict__ Wt,
    const float* __restrict__ bias,
    unsigned short* __restrict__ Qs, unsigned short* __restrict__ Ks,
    unsigned short* __restrict__ Vt) {
  __shared__ __align__(1024) char lsA[16384];
  __shared__ __align__(1024) char lsB[32768];
  int bid = (blockIdx.x & 7) * 144 + (blockIdx.x >> 3);   // bijective XCD swizzle
  int mt = bid / 9, ntb = bid % 9;
  int m0 = mt * 128, n0 = ntb * 256;

  int tid = threadIdx.x, lane = tid & 63, wid = tid >> 6;
  int c8 = (lane & 7) ^ (lane >> 3);
  int rloc = (lane >> 3) * 2 + (c8 >> 2), colo = (c8 & 3) * 8;

  const unsigned short* gA = xb + (size_t)(m0 + rloc) * DIM + colo;
  const unsigned short* gB = Wt + (size_t)(n0 + rloc) * DIM + colo;

  f32x4 acc[8][4] = {};
  gemm_core(gA, gB, DIM, DIM, lsA, lsB, 24, wid, lane, acc);

  int lr = lane & 15, lg = lane >> 4;
  float bia[4];
#pragma unroll
  for (int n = 0; n < 4; ++n) bia[n] = bias[n0 + wid * 64 + n * 16 + lr];

  if (ntb < 3) {          // Q: * alpha^s / sqrt(d)
#pragma unroll
    for (int f = 0; f < 8; ++f)
#pragma unroll
      for (int r = 0; r < 4; ++r) {
        int mg = m0 + f * 16 + lg * 4 + r;
        int b = mg >> 10, s = mg & 1023;
        float sc = exp2f((float)s * L2A) * RSQRTD;
        unsigned short* dst = Qs + ((size_t)b * SEQ + s) * DIM + n0 + wid * 64 + lr;
#pragma unroll
        for (int n = 0; n < 4; ++n)
          dst[n * 16] = f2bf((acc[f][n][r] + bia[n]) * sc);
      }
  } else if (ntb < 6) {   // K: * alpha^(-s)
#pragma unroll
    for (int f = 0; f < 8; ++f)
#pragma unroll
      for (int r = 0; r < 4; ++r) {
        int mg = m0 + f * 16 + lg * 4 + r;
        int b = mg >> 10, s = mg & 1023;
        float sc = exp2f(-(float)s * L2A);
        unsigned short* dst = Ks + ((size_t)b * SEQ + s) * DIM + (n0 - DIM) + wid * 64 + lr;
#pragma unroll
        for (int n = 0; n < 4; ++n)
          dst[n * 16] = f2bf((acc[f][n][r] + bia[n]) * sc);
      }
  } else {                // V: transpose to Vt[b][d][s]; r runs along s -> 8B stores
#pragma unroll
    for (int f = 0; f < 8; ++f) {
      int mg = m0 + f * 16 + lg * 4;
      int b = mg >> 10, s0 = mg & 1023;
#pragma unroll
      for (int n = 0; n < 4; ++n) {
        int d = (n0 - 2 * DIM) + wid * 64 + n * 16 + lr;
        ushort4 v;
        v.x = f2bf(acc[f][n][0] + bia[n]);
        v.y = f2bf(acc[f][n][1] + bia[n]);
        v.z = f2bf(acc[f][n][2] + bia[n]);
        v.w = f2bf(acc[f][n][3] + bia[n]);
        *(ushort4*)(Vt + ((size_t)b * DIM + d) * SEQ + s0) = v;
      }
    }
  }
}

// ---------------- scores: Sm[bl][i][j] = tril(Q' @ K'^T). 20 tiles/batch (i:128, j:256)
__constant__ const signed char IT_TAB[20] = {0,1,2,2,3,3,4,4,4,5,5,5,6,6,6,6,7,7,7,7};
__constant__ const signed char JT_TAB[20] = {0,0,0,1,0,1,0,1,2,0,1,2,0,1,2,3,0,1,2,3};

__global__ void __launch_bounds__(256, 2) score_g(
    const unsigned short* __restrict__ Qs, const unsigned short* __restrict__ Ks,
    unsigned short* __restrict__ Sm, int b_base) {
  __shared__ __align__(1024) char lsA[16384];
  __shared__ __align__(1024) char lsB[32768];
  int bid = (blockIdx.x & 7) * (gridDim.x >> 3) + (blockIdx.x >> 3);
  int idx = bid % 20, bl = bid / 20;
  int b = b_base + bl;
  int m0 = IT_TAB[idx] * 128, n0 = JT_TAB[idx] * 256;
  const unsigned short* A  = Qs + (size_t)b * SEQ * DIM;
  const unsigned short* Bt = Ks + (size_t)b * SEQ * DIM;
  unsigned short* Smp = Sm + (size_t)bl * SEQ * SEQ;

  int tid = threadIdx.x, lane = tid & 63, wid = tid >> 6;
  int c8 = (lane & 7) ^ (lane >> 3);
  int rloc = (lane >> 3) * 2 + (c8 >> 2), colo = (c8 & 3) * 8;

  const unsigned short* gA = A  + (size_t)(m0 + rloc) * DIM + colo;
  const unsigned short* gB = Bt + (size_t)(n0 + rloc) * DIM + colo;

  f32x4 acc[8][4] = {};
  gemm_core(gA, gB, DIM, DIM, lsA, lsB, 24, wid, lane, acc);

  int lr = lane & 15, lg = lane >> 4;
#pragma unroll
  for (int f = 0; f < 8; ++f)
#pragma unroll
    for (int n = 0; n < 4; ++n) {
      int j = n0 + wid * 64 + n * 16 + lr;
#pragma unroll
      for (int r = 0; r < 4; ++r) {
        int i = m0 + f * 16 + lg * 4 + r;
        float v = acc[f][n][r];
        if (j > i) v = 0.0f;   // causal mask
        Smp[(size_t)i * SEQ + j] = f2bf(v);
      }
    }
}

// ---------------- PV: out[b][i][d] = Sm[bl] @ V; tiles (i:128, d:256), heavy-first
__global__ void __launch_bounds__(256, 2) pv_g(
    const unsigned short* __restrict__ Sm, const unsigned short* __restrict__ Vt,
    float* __restrict__ out, int b_base, int gsz) {
  __shared__ __align__(1024) char lsA[16384];
  __shared__ __align__(1024) char lsB[32768];
  int bid = (blockIdx.x & 7) * (gridDim.x >> 3) + (blockIdx.x >> 3);
  int it = 7 - bid / (gsz * 3);            // heavy (large kmax) first
  int rem = bid % (gsz * 3);
  int bl = rem / 3, dt = rem % 3;
  int b = b_base + bl;
  int m0 = it * 128, n0 = dt * 256;
  const unsigned short* A  = Sm + (size_t)bl * SEQ * SEQ;   // ld 1024
  const unsigned short* Bt = Vt + (size_t)b * DIM * SEQ;    // ld 1024
  int nt = (it + 1) * 4;                   // K-tiles of 32, causal bound (>=4)

  int tid = threadIdx.x, lane = tid & 63, wid = tid >> 6;
  int c8 = (lane & 7) ^ (lane >> 3);
  int rloc = (lane >> 3) * 2 + (c8 >> 2), colo = (c8 & 3) * 8;

  const unsigned short* gA = A  + (size_t)(m0 + rloc) * SEQ + colo;
  const unsigned short* gB = Bt + (size_t)(n0 + rloc) * SEQ + colo;

  f32x4 acc[8][4] = {};
  gemm_core(gA, gB, SEQ, SEQ, lsA, lsB, nt, wid, lane, acc);

  int lr = lane & 15, lg = lane >> 4;
#pragma unroll
  for (int f = 0; f < 8; ++f)
#pragma unroll
    for (int n = 0; n < 4; ++n) {
      int d = n0 + wid * 64 + n * 16 + lr;
#pragma unroll
      for (int r = 0; r < 4; ++r) {
        int i = m0 + f * 16 + lg * 4 + r;
        out[((size_t)b * SEQ + i) * DIM + d] = acc[f][n][r];
      }
    }
}

extern "C" void kernel_launch(void* const* d_in, const int* in_sizes, int n_in,
                              void* d_out, int out_size, void* d_ws, size_t ws_size,
                              hipStream_t stream) {
  const float* x    = (const float*)d_in[0];
  const float* W    = (const float*)d_in[1];
  const float* bias = (const float*)d_in[2];
  float* out = (float*)d_out;

  char* ws = (char*)d_ws;
  // ws: Wt 3.5MB | Qs/Ks/Vt 25.2MB each | Sm 16.8MB (8 batches) or 33.6MB (16)
  unsigned short* Wt = (unsigned short*)(ws);
  unsigned short* Qs = (unsigned short*)(ws + 3538944);
  unsigned short* Ks = (unsigned short*)(ws + 3538944 + 25165824);
  unsigned short* Vt = (unsigned short*)(ws + 3538944 + 2 * 25165824);
  unsigned short* Sm = (unsigned short*)(ws + 3538944 + 3 * 25165824);
  // bf16 x lives in d_out (50.3MB >= 25.2MB); fully consumed by qkv before pv writes.
  unsigned short* xb = (unsigned short*)d_out;

  size_t smBase = 3538944 + 3 * (size_t)25165824;
  int gsz = (ws_size >= smBase + (size_t)16 * SEQ * SEQ * 2) ? 16 : 8;
  int ngrp = 16 / gsz;

  prep<<<6576, 256, 0, stream>>>(x, xb, W, Wt);
  qkv_g<<<1152, 256, 0, stream>>>(xb, Wt, bias, Qs, Ks, Vt);
  for (int g = 0; g < ngrp; ++g) {
    score_g<<<gsz * 20, 256, 0, stream>>>(Qs, Ks, Sm, g * gsz);
    pv_g<<<gsz * 24, 256, 0, stream>>>(Sm, Vt, out, g * gsz, gsz);
  }
}

// Round 9
// 165.721 us; speedup vs baseline: 1.0622x; 1.0622x over previous
//
#include <hip/hip_runtime.h>
#include <hip/hip_bf16.h>

// Retention: out = (tril(alpha^(i-j)) * (QK^T/sqrt(d))) @ V, qkv = x@W + b
// Decay folded into operands: Q' = q*alpha^i/sqrt(d), K' = k*alpha^(-j)
// Shared GEMM core = m97 geometry (the 874-912 TF verified reference):
//   128x128 tile, 4 waves (2x2, per-wave 64x64, acc[4][4]), K-step 32,
//   SINGLE-buffered LDS (16KB total -> 3-4 blocks/CU), plain __syncthreads loop,
//   global_load_lds(16B) staging. Upgrade over m97: the r6/r8-verified
//   zero-conflict LDS packing (2 rows per 128B line, slot = ((r&1)*4+lg)^((r>>1)&7)),
//   applied as pre-swizzled global source + swizzled ds_read (LDS dest linear).
// TLP from co-resident blocks hides the barrier drain (m114) - the thing every
// deeper-pipelined variant of rounds 6-8 lost.

#define SEQ   1024
#define DIM   768
#define ND3   2304

typedef __attribute__((ext_vector_type(8))) short bf16x8;
typedef __attribute__((ext_vector_type(4))) float f32x4;

#define L2A     (-0.014499569695115089f)   // log2(0.99)
#define RSQRTD  (0.03608439182435161f)     // 1/sqrt(768)

__device__ __forceinline__ unsigned short f2bf(float x) {
  union { float f; unsigned u; } v; v.f = x;
  unsigned r = v.u + 0x7FFFu + ((v.u >> 16) & 1u);
  return (unsigned short)(r >> 16);
}

__device__ __forceinline__ void gload16(const void* g, void* l) {
  __builtin_amdgcn_global_load_lds(
      (const __attribute__((address_space(1))) void*)g,
      (__attribute__((address_space(3))) void*)l, 16, 0, 0);
}

// ---- core: acc[4][4] += A[128 x nt*32] @ B[128 x nt*32]^T (row-major, K contig)
// gA/gB are per-lane pre-swizzled sources:
//   c8 = (lane&7)^(lane>>3); rloc = (lane>>3)*2 + (c8>>2); colo = (c8&3)*8
//   gA = Abase + (m0 + rloc)*ldA + colo   (likewise gB with n0/ldB)
// LDS per operand: 64 lines x 128B = 8KB; line a slot b holds row 2a+((b^a)>>2),
// 16B-unit ((b^a)&3). Read slot = ((parity<<2)|lg) ^ (line&7)  [0-conflict, r6/r8].
__device__ __forceinline__ void gemm_core(
    const unsigned short* gA, const unsigned short* gB, int ldA, int ldB,
    char* lsA, char* lsB, int nt, int wid, int lane, f32x4 acc[4][4]) {
  int lr = lane & 15, lg = lane >> 4;
  int wm = wid >> 1, wn = wid & 1;
  int slot16 = (((((lr & 1) << 2) | lg) ^ ((lr >> 1) & 7)) << 4);
  int rdA = wm * 4096 + (lr >> 1) * 128 + slot16;   // + f*1024
  int rdB = wn * 4096 + (lr >> 1) * 128 + slot16;   // + n*1024

  for (int t = 0; t < nt; ++t) {
    // stage K-step t: wave wid stages rows [wid*32, wid*32+32) of A and B
    {
      const unsigned short* sa = gA + (size_t)(wid * 32) * ldA + t * 32;
      const unsigned short* sb = gB + (size_t)(wid * 32) * ldB + t * 32;
      gload16(sa, lsA + wid * 2048);
      gload16(sa + (size_t)16 * ldA, lsA + wid * 2048 + 1024);
      gload16(sb, lsB + wid * 2048);
      gload16(sb + (size_t)16 * ldB, lsB + wid * 2048 + 1024);
    }
    __syncthreads();                      // drains vmcnt: tile visible to block
    bf16x8 aF[4], bF[4];
#pragma unroll
    for (int f = 0; f < 4; ++f)
      aF[f] = *(const bf16x8*)(lsA + rdA + f * 1024);
#pragma unroll
    for (int n = 0; n < 4; ++n)
      bF[n] = *(const bf16x8*)(lsB + rdB + n * 1024);
    __builtin_amdgcn_s_setprio(1);
#pragma unroll
    for (int f = 0; f < 4; ++f)
#pragma unroll
      for (int n = 0; n < 4; ++n)
        acc[f][n] = __builtin_amdgcn_mfma_f32_16x16x32_bf16(aF[f], bF[n], acc[f][n], 0, 0, 0);
    __builtin_amdgcn_s_setprio(0);
    __syncthreads();                      // all reads done before next overwrite
  }
}

// ---------------- prep: convert x f32->bf16 (6144 blocks) + transpose W (432)
__global__ void prep(const float* __restrict__ x, unsigned short* __restrict__ xb,
                     const float* __restrict__ W, unsigned short* __restrict__ Wt) {
  __shared__ float tile[64][65];
  int bid = blockIdx.x;
  if (bid < 6144) {               // convert_x
    size_t i = ((size_t)bid * 256 + threadIdx.x) * 8;
    float4 f0 = *(const float4*)(x + i);
    float4 f1 = *(const float4*)(x + i + 4);
    bf16x8 v;
    v[0] = (short)f2bf(f0.x); v[1] = (short)f2bf(f0.y);
    v[2] = (short)f2bf(f0.z); v[3] = (short)f2bf(f0.w);
    v[4] = (short)f2bf(f1.x); v[5] = (short)f2bf(f1.y);
    v[6] = (short)f2bf(f1.z); v[7] = (short)f2bf(f1.w);
    *(bf16x8*)(xb + i) = v;
  } else {                        // transpose_w
    int tb = bid - 6144;
    int n0 = (tb % 36) * 64;
    int k0 = (tb / 36) * 64;
    int tx = threadIdx.x & 63, ty = threadIdx.x >> 6;
#pragma unroll
    for (int p = 0; p < 16; ++p) {
      int k = ty + p * 4;
      tile[k][tx] = W[(size_t)(k0 + k) * ND3 + n0 + tx];
    }
    __syncthreads();
#pragma unroll
    for (int p = 0; p < 16; ++p) {
      int n = ty + p * 4;
      Wt[(size_t)(n0 + n) * DIM + k0 + tx] = f2bf(tile[tx][n]);
    }
  }
}

// ---------------- QKV: xb[16384][768] @ Wt^T -> Q',K',Vt. grid 2304 = 128mt x 18nt
__global__ void __launch_bounds__(256) qkv_g(
    const unsigned short* __restrict__ xb, const unsigned short* __restrict__ Wt,
    const float* __restrict__ bias,
    unsigned short* __restrict__ Qs, unsigned short* __restrict__ Ks,
    unsigned short* __restrict__ Vt) {
  __shared__ __align__(1024) char lsA[8192];
  __shared__ __align__(1024) char lsB[8192];
  int bid = (blockIdx.x & 7) * 288 + (blockIdx.x >> 3);   // bijective XCD swizzle
  int mt = bid / 18, ntb = bid % 18;
  int m0 = mt * 128, n0 = ntb * 128;

  int tid = threadIdx.x, lane = tid & 63, wid = tid >> 6;
  int c8 = (lane & 7) ^ (lane >> 3);
  int rloc = (lane >> 3) * 2 + (c8 >> 2), colo = (c8 & 3) * 8;

  const unsigned short* gA = xb + (size_t)(m0 + rloc) * DIM + colo;
  const unsigned short* gB = Wt + (size_t)(n0 + rloc) * DIM + colo;

  f32x4 acc[4][4] = {};
  gemm_core(gA, gB, DIM, DIM, lsA, lsB, 24, wid, lane, acc);

  int wm = wid >> 1, wn = wid & 1;
  int lr = lane & 15, lg = lane >> 4;
  float bia[4];
#pragma unroll
  for (int n = 0; n < 4; ++n) bia[n] = bias[n0 + wn * 64 + n * 16 + lr];

  if (ntb < 6) {           // Q: * alpha^s / sqrt(d)
#pragma unroll
    for (int f = 0; f < 4; ++f)
#pragma unroll
      for (int r = 0; r < 4; ++r) {
        int mg = m0 + wm * 64 + f * 16 + lg * 4 + r;
        int b = mg >> 10, s = mg & 1023;
        float sc = exp2f((float)s * L2A) * RSQRTD;
        unsigned short* dst = Qs + ((size_t)b * SEQ + s) * DIM + n0 + wn * 64 + lr;
#pragma unroll
        for (int n = 0; n < 4; ++n)
          dst[n * 16] = f2bf((acc[f][n][r] + bia[n]) * sc);
      }
  } else if (ntb < 12) {   // K: * alpha^(-s)
#pragma unroll
    for (int f = 0; f < 4; ++f)
#pragma unroll
      for (int r = 0; r < 4; ++r) {
        int mg = m0 + wm * 64 + f * 16 + lg * 4 + r;
        int b = mg >> 10, s = mg & 1023;
        float sc = exp2f(-(float)s * L2A);
        unsigned short* dst = Ks + ((size_t)b * SEQ + s) * DIM + (n0 - DIM) + wn * 64 + lr;
#pragma unroll
        for (int n = 0; n < 4; ++n)
          dst[n * 16] = f2bf((acc[f][n][r] + bia[n]) * sc);
      }
  } else {                 // V: transpose to Vt[b][d][s]; r runs along s -> 8B stores
#pragma unroll
    for (int f = 0; f < 4; ++f) {
      int mg = m0 + wm * 64 + f * 16 + lg * 4;
      int b = mg >> 10, s0 = mg & 1023;
#pragma unroll
      for (int n = 0; n < 4; ++n) {
        int d = (n0 - 2 * DIM) + wn * 64 + n * 16 + lr;
        ushort4 v;
        v.x = f2bf(acc[f][n][0] + bia[n]);
        v.y = f2bf(acc[f][n][1] + bia[n]);
        v.z = f2bf(acc[f][n][2] + bia[n]);
        v.w = f2bf(acc[f][n][3] + bia[n]);
        *(ushort4*)(Vt + ((size_t)b * DIM + d) * SEQ + s0) = v;
      }
    }
  }
}

// ---------------- scores: Sm[bl][i][j] = tril(Q' @ K'^T). 36 tril 128^2 tiles/batch
__global__ void __launch_bounds__(256) score_g(
    const unsigned short* __restrict__ Qs, const unsigned short* __restrict__ Ks,
    unsigned short* __restrict__ Sm, int b_base) {
  __shared__ __align__(1024) char lsA[8192];
  __shared__ __align__(1024) char lsB[8192];
  int bid = (blockIdx.x & 7) * (gridDim.x >> 3) + (blockIdx.x >> 3);
  int t = bid % 36, bl = bid / 36;
  int b = b_base + bl;
  int it = 0;
  while (t >= it + 1) { t -= it + 1; it++; }
  int jt = t;
  int m0 = it * 128, n0 = jt * 128;
  const unsigned short* A  = Qs + (size_t)b * SEQ * DIM;
  const unsigned short* Bt = Ks + (size_t)b * SEQ * DIM;
  unsigned short* Smp = Sm + (size_t)bl * SEQ * SEQ;

  int tid = threadIdx.x, lane = tid & 63, wid = tid >> 6;
  int c8 = (lane & 7) ^ (lane >> 3);
  int rloc = (lane >> 3) * 2 + (c8 >> 2), colo = (c8 & 3) * 8;

  const unsigned short* gA = A  + (size_t)(m0 + rloc) * DIM + colo;
  const unsigned short* gB = Bt + (size_t)(n0 + rloc) * DIM + colo;

  f32x4 acc[4][4] = {};
  gemm_core(gA, gB, DIM, DIM, lsA, lsB, 24, wid, lane, acc);

  int wm = wid >> 1, wn = wid & 1;
  int lr = lane & 15, lg = lane >> 4;
#pragma unroll
  for (int f = 0; f < 4; ++f)
#pragma unroll
    for (int n = 0; n < 4; ++n) {
      int j = n0 + wn * 64 + n * 16 + lr;
#pragma unroll
      for (int r = 0; r < 4; ++r) {
        int i = m0 + wm * 64 + f * 16 + lg * 4 + r;
        float v = acc[f][n][r];
        if (j > i) v = 0.0f;   // causal mask (bites only on diagonal tiles)
        Smp[(size_t)i * SEQ + j] = f2bf(v);
      }
    }
}

// ---------------- PV: out[b][i][d] = Sm[bl] @ V; (i:128, d:128), heavy-first
__global__ void __launch_bounds__(256) pv_g(
    const unsigned short* __restrict__ Sm, const unsigned short* __restrict__ Vt,
    float* __restrict__ out, int b_base, int gsz) {
  __shared__ __align__(1024) char lsA[8192];
  __shared__ __align__(1024) char lsB[8192];
  int band = gsz * 6;                       // blocks per i-tile band (mult of 8)
  int it = 7 - blockIdx.x / band;           // heavy (large kmax) first in dispatch order
  int sub = blockIdx.x % band;
  sub = (sub & 7) * (band >> 3) + (sub >> 3);   // XCD swizzle within band
  int bl = sub / 6, dt = sub % 6;
  int b = b_base + bl;
  int m0 = it * 128, n0 = dt * 128;
  const unsigned short* A  = Sm + (size_t)bl * SEQ * SEQ;   // ld 1024
  const unsigned short* Bt = Vt + (size_t)b * DIM * SEQ;    // ld 1024
  int nt = (it + 1) * 4;                    // K-steps of 32, causal bound

  int tid = threadIdx.x, lane = tid & 63, wid = tid >> 6;
  int c8 = (lane & 7) ^ (lane >> 3);
  int rloc = (lane >> 3) * 2 + (c8 >> 2), colo = (c8 & 3) * 8;

  const unsigned short* gA = A  + (size_t)(m0 + rloc) * SEQ + colo;
  const unsigned short* gB = Bt + (size_t)(n0 + rloc) * SEQ + colo;

  f32x4 acc[4][4] = {};
  gemm_core(gA, gB, SEQ, SEQ, lsA, lsB, nt, wid, lane, acc);

  int wm = wid >> 1, wn = wid & 1;
  int lr = lane & 15, lg = lane >> 4;
#pragma unroll
  for (int f = 0; f < 4; ++f)
#pragma unroll
    for (int n = 0; n < 4; ++n) {
      int d = n0 + wn * 64 + n * 16 + lr;
#pragma unroll
      for (int r = 0; r < 4; ++r) {
        int i = m0 + wm * 64 + f * 16 + lg * 4 + r;
        out[((size_t)b * SEQ + i) * DIM + d] = acc[f][n][r];
      }
    }
}

extern "C" void kernel_launch(void* const* d_in, const int* in_sizes, int n_in,
                              void* d_out, int out_size, void* d_ws, size_t ws_size,
                              hipStream_t stream) {
  const float* x    = (const float*)d_in[0];
  const float* W    = (const float*)d_in[1];
  const float* bias = (const float*)d_in[2];
  float* out = (float*)d_out;

  char* ws = (char*)d_ws;
  // ws: Wt 3.5MB | Qs/Ks/Vt 25.2MB each | Sm 16.8MB (8 batches) or 33.6MB (16)
  unsigned short* Wt = (unsigned short*)(ws);
  unsigned short* Qs = (unsigned short*)(ws + 3538944);
  unsigned short* Ks = (unsigned short*)(ws + 3538944 + 25165824);
  unsigned short* Vt = (unsigned short*)(ws + 3538944 + 2 * 25165824);
  unsigned short* Sm = (unsigned short*)(ws + 3538944 + 3 * 25165824);
  // bf16 x lives in d_out (50.3MB >= 25.2MB); fully consumed by qkv before pv writes.
  unsigned short* xb = (unsigned short*)d_out;

  size_t smBase = 3538944 + 3 * (size_t)25165824;
  int gsz = (ws_size >= smBase + (size_t)16 * SEQ * SEQ * 2) ? 16 : 8;
  int ngrp = 16 / gsz;

  prep<<<6576, 256, 0, stream>>>(x, xb, W, Wt);
  qkv_g<<<2304, 256, 0, stream>>>(xb, Wt, bias, Qs, Ks, Vt);
  for (int g = 0; g < ngrp; ++g) {
    score_g<<<gsz * 36, 256, 0, stream>>>(Qs, Ks, Sm, g * gsz);
    pv_g<<<gsz * 48, 256, 0, stream>>>(Sm, Vt, out, g * gsz, gsz);
  }
}

// Round 10
// 152.294 us; speedup vs baseline: 1.1558x; 1.0882x over previous
//
#include <hip/hip_runtime.h>
#include <hip/hip_bf16.h>

// Retention: out = (tril(alpha^(i-j)) * (QK^T/sqrt(d))) @ V, qkv = x@W + b
// Decay folded into operands: Q' = q*alpha^i/sqrt(d), K' = k*alpha^(-j)
// qkv: r4 structure (128x256 tile, BK=32 dbuf, 8 waves of 64x64, counted
//   vmcnt(3) gate, 48KB LDS) + the r6/r9-verified ZERO-conflict LDS packing
//   (2 rows per 128B line, slot = ((row&1)*4+lg)^((row>>1)&7); pre-swizzled
//   global source, linear gload_lds dest). Single-variable vs r4: conflict fix.
// score/pv: r5 verbatim (BK=64 dbuf 128^2 core, measured 0 conflicts, proven).

#define SEQ   1024
#define DIM   768
#define ND3   2304

typedef __attribute__((ext_vector_type(8))) short bf16x8;
typedef __attribute__((ext_vector_type(4))) float f32x4;

#define L2A     (-0.014499569695115089f)   // log2(0.99)
#define RSQRTD  (0.03608439182435161f)     // 1/sqrt(768)

__device__ __forceinline__ unsigned short f2bf(float x) {
  union { float f; unsigned u; } v; v.f = x;
  unsigned r = v.u + 0x7FFFu + ((v.u >> 16) & 1u);
  return (unsigned short)(r >> 16);
}

__device__ __forceinline__ void gload16(const void* g, void* l) {
  __builtin_amdgcn_global_load_lds(
      (const __attribute__((address_space(1))) void*)g,
      (__attribute__((address_space(3))) void*)l, 16, 0, 0);
}

// ---------------- prep: convert x f32->bf16 (6144 blocks) + transpose W (432)
__global__ void prep(const float* __restrict__ x, unsigned short* __restrict__ xb,
                     const float* __restrict__ W, unsigned short* __restrict__ Wt) {
  __shared__ float tile[64][65];
  int bid = blockIdx.x;
  if (bid < 6144) {               // convert_x
    size_t i = ((size_t)bid * 256 + threadIdx.x) * 8;
    float4 f0 = *(const float4*)(x + i);
    float4 f1 = *(const float4*)(x + i + 4);
    bf16x8 v;
    v[0] = (short)f2bf(f0.x); v[1] = (short)f2bf(f0.y);
    v[2] = (short)f2bf(f0.z); v[3] = (short)f2bf(f0.w);
    v[4] = (short)f2bf(f1.x); v[5] = (short)f2bf(f1.y);
    v[6] = (short)f2bf(f1.z); v[7] = (short)f2bf(f1.w);
    *(bf16x8*)(xb + i) = v;
  } else {                        // transpose_w
    int tb = bid - 6144;
    int n0 = (tb % 36) * 64;
    int k0 = (tb / 36) * 64;
    int tx = threadIdx.x & 63, ty = threadIdx.x >> 6;
#pragma unroll
    for (int p = 0; p < 16; ++p) {
      int k = ty + p * 4;
      tile[k][tx] = W[(size_t)(k0 + k) * ND3 + n0 + tx];
    }
    __syncthreads();
#pragma unroll
    for (int p = 0; p < 16; ++p) {
      int n = ty + p * 4;
      Wt[(size_t)(n0 + n) * DIM + k0 + tx] = f2bf(tile[tx][n]);
    }
  }
}

// ---------------- QKV: xb[16384][768] @ Wt^T -> Q',K',Vt. grid 1152 = 128mt x 9nt
// 128x256 tile, BK=32 dbuf, 8 waves (2M x 4N, 64x64 each, acc[4][4]).
// LDS: A 2x8KB, B 2x16KB. Chunk = 16 rows in 8 lines (2 rows/128B line).
// line a slot b holds row 2a+((b^a)>>2), 16B-unit (b^a)&3  [0-conflict, r6/r9].
__global__ void __launch_bounds__(512, 4) qkv_g(
    const unsigned short* __restrict__ xb, const unsigned short* __restrict__ Wt,
    const float* __restrict__ bias,
    unsigned short* __restrict__ Qs, unsigned short* __restrict__ Ks,
    unsigned short* __restrict__ Vt) {
  __shared__ __align__(1024) char lsA[16384];
  __shared__ __align__(1024) char lsB[32768];
  int bid = (blockIdx.x & 7) * 144 + (blockIdx.x >> 3);   // bijective XCD swizzle
  int mt = bid / 9, ntb = bid % 9;
  int m0 = mt * 128, n0 = ntb * 256;

  int tid = threadIdx.x, lane = tid & 63, wid = tid >> 6;
  int lr = lane & 15, lg = lane >> 4;
  int wm = wid >> 2, wn = wid & 3;
  // staging pre-swizzle (per-lane source), r9-proven
  int c8 = (lane & 7) ^ (lane >> 3);
  int rloc = (lane >> 3) * 2 + (c8 >> 2), colo = (c8 & 3) * 8;
  const unsigned short* gA = xb + (size_t)(m0 + rloc) * DIM + colo;
  const unsigned short* gB = Wt + (size_t)(n0 + rloc) * DIM + colo;
  // read offsets
  int slot16 = (((((lr & 1) << 2) | lg) ^ ((lr >> 1) & 7)) << 4);
  int rdA = wm * 4096 + (lr >> 1) * 128 + slot16;   // + f*1024 + par*8192
  int rdB = wn * 4096 + (lr >> 1) * 128 + slot16;   // + n*1024 + par*16384

  f32x4 acc[4][4] = {};

#define STG(t, par) do {                                                      \
    char* la_ = lsA + (par) * 8192;                                           \
    char* lb_ = lsB + (par) * 16384;                                          \
    gload16(gA + (size_t)(wid * 16) * DIM + (t) * 32, la_ + wid * 1024);      \
    gload16(gB + (size_t)(wid * 32) * DIM + (t) * 32, lb_ + wid * 2048);      \
    gload16(gB + (size_t)(wid * 32 + 16) * DIM + (t) * 32,                    \
            lb_ + wid * 2048 + 1024);                                         \
  } while (0)

  STG(0, 0);
  STG(1, 1);
  asm volatile("s_waitcnt vmcnt(3)" ::: "memory");   // tile 0 ready
  __builtin_amdgcn_s_barrier();
  asm volatile("" ::: "memory");

  for (int t = 0; t < 24; ++t) {
    int pA = (t & 1) * 8192, pB = (t & 1) * 16384;
    bf16x8 aF[4], bF[4];
#pragma unroll
    for (int f = 0; f < 4; ++f)
      aF[f] = *(const bf16x8*)(lsA + pA + rdA + f * 1024);
#pragma unroll
    for (int n = 0; n < 4; ++n)
      bF[n] = *(const bf16x8*)(lsB + pB + rdB + n * 1024);
    __builtin_amdgcn_s_setprio(1);
#pragma unroll
    for (int f = 0; f < 4; ++f)
#pragma unroll
      for (int n = 0; n < 4; ++n)
        acc[f][n] = __builtin_amdgcn_mfma_f32_16x16x32_bf16(aF[f], bF[n], acc[f][n], 0, 0, 0);
    __builtin_amdgcn_s_setprio(0);

    if (t == 23) break;
    __builtin_amdgcn_s_barrier();          // all reads of this parity done
    asm volatile("" ::: "memory");
    if (t + 2 < 24) {
      STG(t + 2, t & 1);                   // refill buffer tile t used
      asm volatile("s_waitcnt vmcnt(3)" ::: "memory");   // tile t+1 ready
    } else {
      asm volatile("s_waitcnt vmcnt(0)" ::: "memory");
    }
    __builtin_amdgcn_s_barrier();
    asm volatile("" ::: "memory");
  }
#undef STG

  float bia[4];
#pragma unroll
  for (int n = 0; n < 4; ++n) bia[n] = bias[n0 + wn * 64 + n * 16 + lr];

  if (ntb < 3) {          // Q: * alpha^s / sqrt(d)
#pragma unroll
    for (int f = 0; f < 4; ++f)
#pragma unroll
      for (int r = 0; r < 4; ++r) {
        int mg = m0 + wm * 64 + f * 16 + lg * 4 + r;
        int b = mg >> 10, s = mg & 1023;
        float sc = exp2f((float)s * L2A) * RSQRTD;
        unsigned short* dst = Qs + ((size_t)b * SEQ + s) * DIM + n0 + wn * 64 + lr;
#pragma unroll
        for (int n = 0; n < 4; ++n)
          dst[n * 16] = f2bf((acc[f][n][r] + bia[n]) * sc);
      }
  } else if (ntb < 6) {   // K: * alpha^(-s)
#pragma unroll
    for (int f = 0; f < 4; ++f)
#pragma unroll
      for (int r = 0; r < 4; ++r) {
        int mg = m0 + wm * 64 + f * 16 + lg * 4 + r;
        int b = mg >> 10, s = mg & 1023;
        float sc = exp2f(-(float)s * L2A);
        unsigned short* dst = Ks + ((size_t)b * SEQ + s) * DIM + (n0 - DIM) + wn * 64 + lr;
#pragma unroll
        for (int n = 0; n < 4; ++n)
          dst[n * 16] = f2bf((acc[f][n][r] + bia[n]) * sc);
      }
  } else {                // V: transpose to Vt[b][d][s]; r runs along s -> 8B stores
#pragma unroll
    for (int f = 0; f < 4; ++f) {
      int mg = m0 + wm * 64 + f * 16 + lg * 4;
      int b = mg >> 10, s0 = mg & 1023;
#pragma unroll
      for (int n = 0; n < 4; ++n) {
        int d = (n0 - 2 * DIM) + wn * 64 + n * 16 + lr;
        ushort4 v;
        v.x = f2bf(acc[f][n][0] + bia[n]);
        v.y = f2bf(acc[f][n][1] + bia[n]);
        v.z = f2bf(acc[f][n][2] + bia[n]);
        v.w = f2bf(acc[f][n][3] + bia[n]);
        *(ushort4*)(Vt + ((size_t)b * DIM + d) * SEQ + s0) = v;
      }
    }
  }
}

// ======================= r5 core (BK=64 dbuf, proven) for score/pv ==========
__device__ __forceinline__ void gemm_core(
    const unsigned short* gA, const unsigned short* gA2,
    const unsigned short* gB, const unsigned short* gB2,
    char* lsA, char* lsB, int nt, int wid, int lane, f32x4 acc[2][4]) {
  int lr = lane & 15, lg = lane >> 4;
  int wm = wid >> 1, wn = wid & 1;
  int rdA = (wm * 32 + lr) * 128 + ((lg ^ (lr & 7)) << 4);
  int rdB = (wn * 64 + lr) * 128 + ((lg ^ (lr & 7)) << 4);
  int wo = wid * 2048;

#define STAGE(t, par) do {                                                    \
    int lo_ = ((par) << 14) + wo;                                             \
    gload16(gA  + (size_t)(t) * 64, lsA + lo_);                               \
    gload16(gA2 + (size_t)(t) * 64, lsA + lo_ + 1024);                        \
    gload16(gB  + (size_t)(t) * 64, lsB + lo_);                               \
    gload16(gB2 + (size_t)(t) * 64, lsB + lo_ + 1024);                        \
  } while (0)

  STAGE(0, 0);
  STAGE(1, 1);
  asm volatile("s_waitcnt vmcnt(4)" ::: "memory");
  __builtin_amdgcn_s_barrier();
  asm volatile("" ::: "memory");

  for (int t = 0; t < nt; ++t) {
    int pbase = (t & 1) << 14;
    bf16x8 aF[2][2], bF[2][4];
#pragma unroll
    for (int kh = 0; kh < 2; ++kh) {
#pragma unroll
      for (int f = 0; f < 2; ++f)
        aF[kh][f] = *(const bf16x8*)(lsA + pbase + ((rdA + f * 2048) ^ (kh << 6)));
#pragma unroll
      for (int n = 0; n < 4; ++n)
        bF[kh][n] = *(const bf16x8*)(lsB + pbase + ((rdB + n * 2048) ^ (kh << 6)));
    }
    __builtin_amdgcn_s_setprio(1);
#pragma unroll
    for (int kh = 0; kh < 2; ++kh)
#pragma unroll
      for (int f = 0; f < 2; ++f)
#pragma unroll
        for (int n = 0; n < 4; ++n)
          acc[f][n] = __builtin_amdgcn_mfma_f32_16x16x32_bf16(aF[kh][f], bF[kh][n], acc[f][n], 0, 0, 0);
    __builtin_amdgcn_s_setprio(0);

    if (t == nt - 1) break;
    __builtin_amdgcn_s_barrier();
    asm volatile("" ::: "memory");
    if (t + 2 < nt) {
      STAGE(t + 2, t & 1);
      asm volatile("s_waitcnt vmcnt(4)" ::: "memory");
    } else {
      asm volatile("s_waitcnt vmcnt(0)" ::: "memory");
    }
    __builtin_amdgcn_s_barrier();
    asm volatile("" ::: "memory");
  }
#undef STAGE
}

// scores: Sm[bl][i][j] = tril(Q' @ K'^T). 36 lower-tri 128x128 tiles/batch
__global__ void __launch_bounds__(512, 4) score_g(
    const unsigned short* __restrict__ Qs, const unsigned short* __restrict__ Ks,
    unsigned short* __restrict__ Sm, int b_base) {
  __shared__ __align__(1024) char lsA[32768];
  __shared__ __align__(1024) char lsB[32768];
  int bid = (blockIdx.x & 7) * (gridDim.x >> 3) + (blockIdx.x >> 3);
  int t = bid % 36, bl = bid / 36;
  int b = b_base + bl;
  int it = 0;
  while (t >= it + 1) { t -= it + 1; it++; }
  int jt = t;
  int m0 = it * 128, n0 = jt * 128;
  const unsigned short* A  = Qs + (size_t)b * SEQ * DIM;
  const unsigned short* Bt = Ks + (size_t)b * SEQ * DIM;
  unsigned short* Smp = Sm + (size_t)bl * SEQ * SEQ;

  int tid = threadIdx.x, lane = tid & 63, wid = tid >> 6;
  int l8 = lane >> 3, cs = ((lane & 7) ^ l8) << 3;
  int srow = wid * 16 + l8;

  const unsigned short* gA = A  + (size_t)(m0 + srow) * DIM + cs;
  const unsigned short* gB = Bt + (size_t)(n0 + srow) * DIM + cs;

  f32x4 acc[2][4] = {};
  gemm_core(gA, gA + 8 * DIM, gB, gB + 8 * DIM, lsA, lsB, 12, wid, lane, acc);

  int wm = wid >> 1, wn = wid & 1;
  int lr = lane & 15, lg = lane >> 4;
#pragma unroll
  for (int f = 0; f < 2; ++f)
#pragma unroll
    for (int n = 0; n < 4; ++n) {
      int j = n0 + wn * 64 + n * 16 + lr;
#pragma unroll
      for (int r = 0; r < 4; ++r) {
        int i = m0 + wm * 32 + f * 16 + lg * 4 + r;
        float v = acc[f][n][r];
        if (j > i) v = 0.0f;   // causal mask (bites only on diagonal tiles)
        Smp[(size_t)i * SEQ + j] = f2bf(v);
      }
    }
}

// PV: out[b][i][d] = Sm[bl] @ V; tiles (i:128, d:128), heavy-first
__global__ void __launch_bounds__(512, 4) pv_g(
    const unsigned short* __restrict__ Sm, const unsigned short* __restrict__ Vt,
    float* __restrict__ out, int b_base, int gsz) {
  __shared__ __align__(1024) char lsA[32768];
  __shared__ __align__(1024) char lsB[32768];
  int it = 7 - blockIdx.x / (gsz * 6);     // heavy (large kmax) first
  int rem = blockIdx.x % (gsz * 6);
  int bl = rem / 6, dt = rem % 6;
  int b = b_base + bl;
  int m0 = it * 128, n0 = dt * 128;
  const unsigned short* A  = Sm + (size_t)bl * SEQ * SEQ;
  const unsigned short* Bt = Vt + (size_t)b * DIM * SEQ;
  int nt = (it + 1) * 2;

  int tid = threadIdx.x, lane = tid & 63, wid = tid >> 6;
  int l8 = lane >> 3, cs = ((lane & 7) ^ l8) << 3;
  int srow = wid * 16 + l8;

  const unsigned short* gA = A  + (size_t)(m0 + srow) * SEQ + cs;
  const unsigned short* gB = Bt + (size_t)(n0 + srow) * SEQ + cs;

  f32x4 acc[2][4] = {};
  gemm_core(gA, gA + 8 * SEQ, gB, gB + 8 * SEQ, lsA, lsB, nt, wid, lane, acc);

  int wm = wid >> 1, wn = wid & 1;
  int lr = lane & 15, lg = lane >> 4;
#pragma unroll
  for (int f = 0; f < 2; ++f)
#pragma unroll
    for (int n = 0; n < 4; ++n) {
      int d = n0 + wn * 64 + n * 16 + lr;
#pragma unroll
      for (int r = 0; r < 4; ++r) {
        int i = m0 + wm * 32 + f * 16 + lg * 4 + r;
        out[((size_t)b * SEQ + i) * DIM + d] = acc[f][n][r];
      }
    }
}

extern "C" void kernel_launch(void* const* d_in, const int* in_sizes, int n_in,
                              void* d_out, int out_size, void* d_ws, size_t ws_size,
                              hipStream_t stream) {
  const float* x    = (const float*)d_in[0];
  const float* W    = (const float*)d_in[1];
  const float* bias = (const float*)d_in[2];
  float* out = (float*)d_out;

  char* ws = (char*)d_ws;
  // ws: Wt 3.5MB | Qs/Ks/Vt 25.2MB each | Sm 16.8MB (8 batches) or 33.6MB (16)
  unsigned short* Wt = (unsigned short*)(ws);
  unsigned short* Qs = (unsigned short*)(ws + 3538944);
  unsigned short* Ks = (unsigned short*)(ws + 3538944 + 25165824);
  unsigned short* Vt = (unsigned short*)(ws + 3538944 + 2 * 25165824);
  unsigned short* Sm = (unsigned short*)(ws + 3538944 + 3 * 25165824);
  // bf16 x lives in d_out (50.3MB >= 25.2MB); fully consumed by qkv before pv writes.
  unsigned short* xb = (unsigned short*)d_out;

  size_t smBase = 3538944 + 3 * (size_t)25165824;
  int gsz = (ws_size >= smBase + (size_t)16 * SEQ * SEQ * 2) ? 16 : 8;
  int ngrp = 16 / gsz;

  prep<<<6576, 256, 0, stream>>>(x, xb, W, Wt);
  qkv_g<<<1152, 512, 0, stream>>>(xb, Wt, bias, Qs, Ks, Vt);
  for (int g = 0; g < ngrp; ++g) {
    score_g<<<gsz * 36, 512, 0, stream>>>(Qs, Ks, Sm, g * gsz);
    pv_g<<<gsz * 48, 512, 0, stream>>>(Sm, Vt, out, g * gsz, gsz);
  }
}